// Round 11
// baseline (849.398 us; speedup 1.0000x reference)
//
#include <hip/hip_runtime.h>
#include <hip/hip_bf16.h>
#include <cmath>

// CapsNet forward. conv2 = split-bf16 MFMA (3-product), K-SPLIT x2:
//  grid 1024 = ksp(2) x coh(2) x img(256), XCD-mapped: xcd=bid&7 fixes
//  (ksp,coh,img-parity) per XCD -> L2-resident weight window per chunk phase.
//  Each block: 4 chunks staged to LDS via global_load_lds; N=32/wave;
//  partials merged by atomicAdd into memset-0 xcaps (2 adds from exact 0 =
//  bit-deterministic; bias added by ksp==0 only).
// ws: wstg 21.2 MB | c1g 104.9 MB | xcaps 9.4 MB = 135.5 MB

typedef float f32x4 __attribute__((ext_vector_type(4)));
typedef short s16x8 __attribute__((ext_vector_type(8)));
typedef unsigned int u32;

static __device__ __forceinline__ short f2bf(float x) {
  __hip_bfloat16 h = __float2bfloat16(x);
  return *reinterpret_cast<short*>(&h);
}
static __device__ __forceinline__ float bf2f(short s) {
  __hip_bfloat16 h;
  *reinterpret_cast<short*>(&h) = s;
  return __bfloat162float(h);
}
static __device__ __forceinline__ void stage16(const short* g, short* l) {
  __builtin_amdgcn_global_load_lds(
      (const __attribute__((address_space(1))) u32*)(const void*)g,
      (__attribute__((address_space(3))) u32*)(void*)l, 16, 0, 0);
}

// ---------------- merged prep: w2->wstg  |  conv1->c1g ----------------
__global__ __launch_bounds__(256) void prep_all(
    const float* __restrict__ w2, s16x8* __restrict__ wstg,
    const float* __restrict__ data, const float* __restrict__ w1,
    const float* __restrict__ b1, short* __restrict__ c1g) {
  if (blockIdx.x < 2592) {
    const int gid = blockIdx.x * 256 + threadIdx.x;  // 663,552 = 648*1024
    const int T = gid >> 10;
    const int s = gid & 1023;
    const int kg = s >> 8, co = s & 255;
    const int chunk = T / 81, tap = T - chunk * 81;
    const float* src = w2 + ((size_t)co * 256 + chunk * 32 + kg * 8) * 81 + tap;
    s16x8 hi, lo;
#pragma unroll
    for (int i = 0; i < 8; ++i) {
      const float x = src[i * 81];
      const short h = f2bf(x);
      hi[i] = h;
      lo[i] = f2bf(x - bf2f(h));
    }
    wstg[(size_t)T * 2048 + s] = hi;
    wstg[(size_t)T * 2048 + 1024 + s] = lo;
    return;
  }
  // ---- conv1 -> c1g (512 blocks: img*2 + yh) ----
  const int cb = blockIdx.x - 2592;
  const int img = cb >> 1;
  const int yh = cb & 1;
  const int t = threadIdx.x;
  __shared__ float simg[19 * 36];
  for (int i = t; i < 19 * 28; i += 256) {
    const int r = i / 28, c = i % 28;
    if (yh * 10 + r < 28) simg[r * 36 + c] = data[img * 784 + (yh * 10 + r) * 28 + c];
  }
  __syncthreads();
  for (int task = t; task < 2560; task += 256) {
    const int ci = task & 255;
    const int yl = task >> 8;       // 0..9
    const int y = yh * 10 + yl;
    const float* wr = w1 + ci * 81;
    float acc[20];
    const float bz = b1[ci];
#pragma unroll
    for (int x = 0; x < 20; ++x) acc[x] = bz;
#pragma unroll
    for (int ky = 0; ky < 9; ++ky) {
      float rr[28];
#pragma unroll
      for (int q = 0; q < 7; ++q)
        *(float4*)&rr[q * 4] = *(const float4*)&simg[(yl + ky) * 36 + q * 4];
#pragma unroll
      for (int kx = 0; kx < 9; ++kx) {
        const float w = wr[ky * 9 + kx];
#pragma unroll
        for (int x = 0; x < 20; ++x) acc[x] = fmaf(w, rr[x + kx], acc[x]);
      }
    }
    const int chunk = ci >> 5, cil = ci & 31, kg = cil >> 3, il = cil & 7;
    short* base = c1g + ((size_t)(img * 8 + chunk) * 400) * 64;
    const int kapy = 6 * (y >> 1);
#pragma unroll
    for (int x = 0; x < 20; ++x) {
      const int row = y * 20 + x;
      const int kap = ((x >> 1) + kapy) & 7;
      const float v = fmaxf(acc[x], 0.f);
      const short hi = f2bf(v);
      const short lo = f2bf(v - bf2f(hi));
      base[row * 64 + (((kg + kap) & 7) << 3) + il] = hi;
      base[row * 64 + (((kg + 4 + kap) & 7) << 3) + il] = lo;
    }
  }
}

// ---------------- conv2 via MFMA, N=32/wave, K-split x2 ----------------
__global__ __launch_bounds__(256) void conv2_mfma(
    const short* __restrict__ c1g, const short* __restrict__ wstg,
    const float* __restrict__ b2, float* __restrict__ xcaps) {
  const int t = threadIdx.x;
  const int bid = blockIdx.x;        // 1024
  const int xcd = bid & 7;
  const int ksp = xcd & 1;           // K half
  const int coh = (xcd >> 1) & 1;    // co half
  const int img = (bid >> 3) * 2 + (xcd >> 2);
  const int lane = t & 63;
  const int wv = t >> 6;             // 0..3
  const int r16 = lane & 15;
  const int kg = lane >> 4;

  __shared__ short c1[400 * 64];     // 51,200 B, swizzled [row][slot8][il8]

  int arow[3], kap0[3];
#pragma unroll
  for (int m = 0; m < 3; ++m) {
    int pos = m * 16 + r16;
    if (pos > 35) pos = 35;          // clamped: same-addr broadcast, discarded
    const int oy = pos / 6, ox = pos % 6;
    arow[m] = oy * 40 + ox * 2;
    kap0[m] = ox + 6 * oy;
  }
  int bOff[2], con[2];
  float bias[2];
#pragma unroll
  for (int j = 0; j < 2; ++j) {
    const int co = coh * 128 + wv * 32 + j * 16 + r16;
    con[j] = co;
    bOff[j] = kg * 256 + co;         // s16x8 slot within tap
    bias[j] = (ksp == 0) ? b2[co] : 0.f;  // bias contributed once
  }

  const f32x4 vzero = {0.f, 0.f, 0.f, 0.f};
  f32x4 acc[3][2];
#pragma unroll
  for (int m = 0; m < 3; ++m)
#pragma unroll
    for (int j = 0; j < 2; ++j) acc[m][j] = vzero;

  const s16x8* wsv = (const s16x8*)wstg;

  for (int cc = 0; cc < 4; ++cc) {
    const int chunk = ksp * 4 + cc;
    __syncthreads();  // previous chunk fully consumed
    {
      const short* src = c1g + ((size_t)(img * 8 + chunk) * 400) * 64;
      for (int c = wv; c < 50; c += 4)
        stage16(src + c * 512 + lane * 8, &c1[c * 512]);
    }
    __syncthreads();  // vmcnt drain: chunk staged

    const size_t bb = (size_t)chunk * 81 * 2048;
    s16x8 BHc[2], BLc[2];
#pragma unroll
    for (int j = 0; j < 2; ++j) {
      BHc[j] = wsv[bb + bOff[j]];
      BLc[j] = wsv[bb + bOff[j] + 1024];
    }
    for (int ky = 0; ky < 9; ++ky) {
      const int rbase = ky * 20;
      const int kapky = 6 * (ky >> 1);
#pragma unroll
      for (int kx = 0; kx < 9; ++kx) {
        const int tt = ky * 9 + kx;
        s16x8 BHn[2], BLn[2];
        if (tt < 80) {
          const size_t nb = bb + (size_t)(tt + 1) * 2048;
#pragma unroll
          for (int j = 0; j < 2; ++j) {
            BHn[j] = wsv[nb + bOff[j]];
            BLn[j] = wsv[nb + bOff[j] + 1024];
          }
        }
        s16x8 AH[3], AL[3];
#pragma unroll
        for (int m = 0; m < 3; ++m) {
          const int row = arow[m] + rbase + kx;
          const int kap = kap0[m] + (kx >> 1) + kapky;
          AH[m] = *(const s16x8*)&c1[row * 64 + (((kg + kap) & 7) << 3)];
          AL[m] = *(const s16x8*)&c1[row * 64 + (((kg + 4 + kap) & 7) << 3)];
        }
#pragma unroll
        for (int m = 0; m < 3; ++m)
#pragma unroll
          for (int j = 0; j < 2; ++j)
            acc[m][j] = __builtin_amdgcn_mfma_f32_16x16x32_bf16(AH[m], BHc[j], acc[m][j], 0, 0, 0);
#pragma unroll
        for (int m = 0; m < 3; ++m)
#pragma unroll
          for (int j = 0; j < 2; ++j)
            acc[m][j] = __builtin_amdgcn_mfma_f32_16x16x32_bf16(AL[m], BHc[j], acc[m][j], 0, 0, 0);
#pragma unroll
        for (int m = 0; m < 3; ++m)
#pragma unroll
          for (int j = 0; j < 2; ++j)
            acc[m][j] = __builtin_amdgcn_mfma_f32_16x16x32_bf16(AH[m], BLc[j], acc[m][j], 0, 0, 0);
#pragma unroll
        for (int j = 0; j < 2; ++j) { BHc[j] = BHn[j]; BLc[j] = BLn[j]; }
      }
    }
  }

  // merge partials: xcaps was memset to 0; exactly 2 atomic adds per element
  // from exact zero are order-independent (fp32 add commutative) -> deterministic
#pragma unroll
  for (int m = 0; m < 3; ++m) {
#pragma unroll
    for (int jj = 0; jj < 4; ++jj) {
      const int pos = m * 16 + kg * 4 + jj;
      if (pos < 36) {
#pragma unroll
        for (int j = 0; j < 2; ++j) {
          const int co = con[j];
          const int n = (co & 31) * 36 + pos;
          atomicAdd(&xcaps[((size_t)img * 1152 + n) * 8 + (co >> 5)],
                    acc[m][j][jj] + bias[j]);
        }
      }
    }
  }
}

// ---------------- fused u_hat + routing: block per (o, image-pair) ----------------
__global__ __launch_bounds__(256) void routing_fused(const float* __restrict__ xcaps,
                                                     const float* __restrict__ W,
                                                     float* __restrict__ out) {
  const int o = blockIdx.x >> 7;     // 0..9
  const int bp = blockIdx.x & 127;   // image pair
  const int b0 = bp * 2, b1 = b0 + 1;
  const int t = threadIdx.x;
  const int k = t & 15, ng = t >> 4;
  __shared__ float xs0[1152 * 8];
  __shared__ float xs1[1152 * 8];
  __shared__ double redA[256], redB[256], redC[256], redD[256];
  __shared__ float s0s[16], s1s[16];
  __shared__ float sv0, sv1;
  __shared__ double f0, f1;

  {
    const float4* src0 = (const float4*)(xcaps + (size_t)b0 * 9216);
    const float4* src1 = (const float4*)(xcaps + (size_t)b1 * 9216);
    float4* d0 = (float4*)xs0;
    float4* d1 = (float4*)xs1;
    for (int i = t; i < 2304; i += 256) { d0[i] = src0[i]; d1[i] = src1[i]; }
  }
  __syncthreads();

  const int n0 = ng * 72;
  float u0[72], u1[72];
  const float* wp = W + ((size_t)(n0 * 10 + o) * 16 + k) * 8;
#pragma unroll
  for (int i = 0; i < 72; ++i) {
    const float* wq = wp + (size_t)i * 1280;
    const float4 wa = *(const float4*)wq;
    const float4 wb = *(const float4*)(wq + 4);
    const float4 xa0 = *(const float4*)&xs0[(n0 + i) * 8];
    const float4 xb0 = *(const float4*)&xs0[(n0 + i) * 8 + 4];
    const float4 xa1 = *(const float4*)&xs1[(n0 + i) * 8];
    const float4 xb1 = *(const float4*)&xs1[(n0 + i) * 8 + 4];
    float s0 = wa.x * xa0.x + wa.y * xa0.y + wa.z * xa0.z + wa.w * xa0.w
             + wb.x * xb0.x + wb.y * xb0.y + wb.z * xb0.z + wb.w * xb0.w;
    float s1 = wa.x * xa1.x + wa.y * xa1.y + wa.z * xa1.z + wa.w * xa1.w
             + wb.x * xb1.x + wb.y * xb1.y + wb.z * xb1.z + wb.w * xb1.w;
    u0[i] = s0;
    u1[i] = s1;
  }

  // ---- pass 1: uniform c = 1/1152 ----
  {
    double S0 = 0.0, S1 = 0.0;
#pragma unroll
    for (int i = 0; i < 72; ++i) { S0 += (double)u0[i]; S1 += (double)u1[i]; }
    redA[t] = S0; redB[t] = S1;
  }
  __syncthreads();
  if (t < 16) {
    double t0 = 0.0, t1 = 0.0;
#pragma unroll
    for (int g = 0; g < 16; ++g) { t0 += redA[g * 16 + t]; t1 += redB[g * 16 + t]; }
    s0s[t] = (float)(t0 * (double)(1.0f / 1152.0f));
    s1s[t] = (float)(t1 * (double)(1.0f / 1152.0f));
  }
  __syncthreads();
  if (t == 0) {
    double sn = 0.0;
#pragma unroll
    for (int kk = 0; kk < 16; ++kk) sn += (double)s0s[kk] * (double)s0s[kk];
    double f = sn / ((1.0 + sn) * sqrt(sn));
    double sv = 0.0;
#pragma unroll
    for (int kk = 0; kk < 16; ++kk) sv += (double)s0s[kk] * f;
    sv0 = (float)sv;
    sn = 0.0;
#pragma unroll
    for (int kk = 0; kk < 16; ++kk) sn += (double)s1s[kk] * (double)s1s[kk];
    f = sn / ((1.0 + sn) * sqrt(sn));
    sv = 0.0;
#pragma unroll
    for (int kk = 0; kk < 16; ++kk) sv += (double)s1s[kk] * f;
    sv1 = (float)sv;
  }
  __syncthreads();
  const float v10 = sv0, v11 = sv1;

  // ---- pass 2: logits u*sv1 ----
  {
    double E0 = 0.0, EU0 = 0.0, E1 = 0.0, EU1 = 0.0;
#pragma unroll
    for (int i = 0; i < 72; ++i) {
      const float e0 = expf(u0[i] * v10);
      E0 += (double)e0;
      EU0 += (double)e0 * (double)u0[i];
      const float e1 = expf(u1[i] * v11);
      E1 += (double)e1;
      EU1 += (double)e1 * (double)u1[i];
    }
    redA[t] = E0; redB[t] = EU0; redC[t] = E1; redD[t] = EU1;
  }
  __syncthreads();
  if (t < 16) {
    double e0 = 0.0, s0 = 0.0, e1 = 0.0, s1 = 0.0;
#pragma unroll
    for (int g = 0; g < 16; ++g) {
      e0 += redA[g * 16 + t]; s0 += redB[g * 16 + t];
      e1 += redC[g * 16 + t]; s1 += redD[g * 16 + t];
    }
    s0s[t] = (float)(s0 / e0);
    s1s[t] = (float)(s1 / e1);
  }
  __syncthreads();
  if (t == 0) {
    double sn = 0.0;
#pragma unroll
    for (int kk = 0; kk < 16; ++kk) sn += (double)s0s[kk] * (double)s0s[kk];
    double f = sn / ((1.0 + sn) * sqrt(sn));
    double sv = 0.0;
#pragma unroll
    for (int kk = 0; kk < 16; ++kk) sv += (double)s0s[kk] * f;
    sv0 = v10 + (float)sv;
    sn = 0.0;
#pragma unroll
    for (int kk = 0; kk < 16; ++kk) sn += (double)s1s[kk] * (double)s1s[kk];
    f = sn / ((1.0 + sn) * sqrt(sn));
    sv = 0.0;
#pragma unroll
    for (int kk = 0; kk < 16; ++kk) sv += (double)s1s[kk] * f;
    sv1 = v11 + (float)sv;
  }
  __syncthreads();
  const float v20 = sv0, v21 = sv1;

  // ---- pass 3 -> output ----
  {
    double E0 = 0.0, EU0 = 0.0, E1 = 0.0, EU1 = 0.0;
#pragma unroll
    for (int i = 0; i < 72; ++i) {
      const float e0 = expf(u0[i] * v20);
      E0 += (double)e0;
      EU0 += (double)e0 * (double)u0[i];
      const float e1 = expf(u1[i] * v21);
      E1 += (double)e1;
      EU1 += (double)e1 * (double)u1[i];
    }
    redA[t] = E0; redB[t] = EU0; redC[t] = E1; redD[t] = EU1;
  }
  __syncthreads();
  if (t < 16) {
    double e0 = 0.0, s0 = 0.0, e1 = 0.0, s1 = 0.0;
#pragma unroll
    for (int g = 0; g < 16; ++g) {
      e0 += redA[g * 16 + t]; s0 += redB[g * 16 + t];
      e1 += redC[g * 16 + t]; s1 += redD[g * 16 + t];
    }
    s0s[t] = (float)(s0 / e0);
    s1s[t] = (float)(s1 / e1);
  }
  __syncthreads();
  if (t == 0) {
    double sn = 0.0;
#pragma unroll
    for (int kk = 0; kk < 16; ++kk) sn += (double)s0s[kk] * (double)s0s[kk];
    f0 = sn / ((1.0 + sn) * sqrt(sn));
    sn = 0.0;
#pragma unroll
    for (int kk = 0; kk < 16; ++kk) sn += (double)s1s[kk] * (double)s1s[kk];
    f1 = sn / ((1.0 + sn) * sqrt(sn));
  }
  __syncthreads();
  if (t < 16) {
    out[b0 * 160 + o * 16 + t] = (float)((double)s0s[t] * f0);
    out[b1 * 160 + o * 16 + t] = (float)((double)s1s[t] * f1);
  }
}

extern "C" void kernel_launch(void* const* d_in, const int* in_sizes, int n_in,
                              void* d_out, int out_size, void* d_ws, size_t ws_size,
                              hipStream_t stream) {
  const float* data = (const float*)d_in[0];
  const float* w1   = (const float*)d_in[1];
  const float* b1   = (const float*)d_in[2];
  const float* w2   = (const float*)d_in[3];
  const float* b2   = (const float*)d_in[4];
  const float* W    = (const float*)d_in[5];
  float* out = (float*)d_out;

  short* wstg  = (short*)d_ws;               // 10,616,832 shorts (21.2 MB)
  short* c1g   = wstg + 10616832;            // 52,428,800 shorts (104.9 MB)
  float* xcaps = (float*)(c1g + 52428800);   //  2,359,296 floats ( 9.4 MB)

  hipMemsetAsync(xcaps, 0, 2359296 * sizeof(float), stream);
  prep_all<<<3104, 256, 0, stream>>>(w2, (s16x8*)wstg, data, w1, b1, c1g);
  conv2_mfma<<<1024, 256, 0, stream>>>(c1g, wstg, b2, xcaps);
  routing_fused<<<1280, 256, 0, stream>>>(xcaps, W, out);
}

// Round 12
// 662.728 us; speedup vs baseline: 1.2817x; 1.2817x over previous
//
#include <hip/hip_runtime.h>
#include <hip/hip_bf16.h>
#include <cmath>

// CapsNet forward. conv2 = split-bf16 MFMA (3-product), R9 structure with LDS
// shaved under the 8KB-granule 3-blocks/CU boundary:
//  c1 chunk buffer = 384 rows x 64 shorts = 49,152 B (rows 0..378 used; conv2
//  k9/s2 never reads input row/col 19, so y=19 is dead).
//  grid 1024 = coh(4) x img(256); 256 thr / 4 waves; N=16/wave; 9 MFMA/tap;
//  chunk staged via global_load_lds; depth-1 B register prefetch.
// ws: wstg 21.2 MB | c1g 100.7 MB | xcaps 9.4 MB = 131.3 MB

typedef float f32x4 __attribute__((ext_vector_type(4)));
typedef short s16x8 __attribute__((ext_vector_type(8)));
typedef unsigned int u32;

static __device__ __forceinline__ short f2bf(float x) {
  __hip_bfloat16 h = __float2bfloat16(x);
  return *reinterpret_cast<short*>(&h);
}
static __device__ __forceinline__ float bf2f(short s) {
  __hip_bfloat16 h;
  *reinterpret_cast<short*>(&h) = s;
  return __bfloat162float(h);
}
static __device__ __forceinline__ void stage16(const short* g, short* l) {
  __builtin_amdgcn_global_load_lds(
      (const __attribute__((address_space(1))) u32*)(const void*)g,
      (__attribute__((address_space(3))) u32*)(void*)l, 16, 0, 0);
}

// ---------------- merged prep: w2->wstg  |  conv1->c1g ----------------
__global__ __launch_bounds__(256) void prep_all(
    const float* __restrict__ w2, s16x8* __restrict__ wstg,
    const float* __restrict__ data, const float* __restrict__ w1,
    const float* __restrict__ b1, short* __restrict__ c1g) {
  if (blockIdx.x < 2592) {
    const int gid = blockIdx.x * 256 + threadIdx.x;  // 663,552 = 648*1024
    const int T = gid >> 10;
    const int s = gid & 1023;
    const int kg = s >> 8, co = s & 255;
    const int chunk = T / 81, tap = T - chunk * 81;
    const float* src = w2 + ((size_t)co * 256 + chunk * 32 + kg * 8) * 81 + tap;
    s16x8 hi, lo;
#pragma unroll
    for (int i = 0; i < 8; ++i) {
      const float x = src[i * 81];
      const short h = f2bf(x);
      hi[i] = h;
      lo[i] = f2bf(x - bf2f(h));
    }
    wstg[(size_t)T * 2048 + s] = hi;
    wstg[(size_t)T * 2048 + 1024 + s] = lo;
    return;
  }
  // ---- conv1 -> c1g (512 blocks: img*2 + yh); y==19 dead for conv2 ----
  const int cb = blockIdx.x - 2592;
  const int img = cb >> 1;
  const int yh = cb & 1;
  const int t = threadIdx.x;
  __shared__ float simg[19 * 36];
  for (int i = t; i < 19 * 28; i += 256) {
    const int r = i / 28, c = i % 28;
    if (yh * 10 + r < 28) simg[r * 36 + c] = data[img * 784 + (yh * 10 + r) * 28 + c];
  }
  __syncthreads();
  for (int task = t; task < 2560; task += 256) {
    const int ci = task & 255;
    const int yl = task >> 8;       // 0..9
    const int y = yh * 10 + yl;
    if (y >= 19) continue;          // dead row
    const float* wr = w1 + ci * 81;
    float acc[20];
    const float bz = b1[ci];
#pragma unroll
    for (int x = 0; x < 20; ++x) acc[x] = bz;
#pragma unroll
    for (int ky = 0; ky < 9; ++ky) {
      float rr[28];
#pragma unroll
      for (int q = 0; q < 7; ++q)
        *(float4*)&rr[q * 4] = *(const float4*)&simg[(yl + ky) * 36 + q * 4];
#pragma unroll
      for (int kx = 0; kx < 9; ++kx) {
        const float w = wr[ky * 9 + kx];
#pragma unroll
        for (int x = 0; x < 20; ++x) acc[x] = fmaf(w, rr[x + kx], acc[x]);
      }
    }
    const int chunk = ci >> 5, cil = ci & 31, kg = cil >> 3, il = cil & 7;
    short* base = c1g + ((size_t)(img * 8 + chunk) * 384) * 64;
    const int kapy = 6 * (y >> 1);
#pragma unroll
    for (int x = 0; x < 20; ++x) {
      const int row = y * 20 + x;   // <= 378
      const int kap = ((x >> 1) + kapy) & 7;
      const float v = fmaxf(acc[x], 0.f);
      const short hi = f2bf(v);
      const short lo = f2bf(v - bf2f(hi));
      base[row * 64 + (((kg + kap) & 7) << 3) + il] = hi;
      base[row * 64 + (((kg + 4 + kap) & 7) << 3) + il] = lo;
    }
  }
}

// ---------------- conv2 via MFMA (R9 structure, 49,152 B LDS) ----------------
__global__ __launch_bounds__(256) void conv2_mfma(
    const short* __restrict__ c1g, const short* __restrict__ wstg,
    const float* __restrict__ b2, float* __restrict__ xcaps) {
  const int t = threadIdx.x;
  const int coh = blockIdx.x >> 8;   // co-major: XCD-mates share a slice
  const int img = blockIdx.x & 255;
  const int lane = t & 63;
  const int wv = t >> 6;             // 0..3
  const int r16 = lane & 15;
  const int kg = lane >> 4;

  __shared__ short c1[384 * 64];     // 49,152 B = 6 x 8KB -> 3 blocks/CU

  int arow[3], kap0[3];
#pragma unroll
  for (int m = 0; m < 3; ++m) {
    int pos = m * 16 + r16;
    if (pos > 35) pos = 35;          // clamped: same-addr broadcast, discarded
    const int oy = pos / 6, ox = pos % 6;
    arow[m] = oy * 40 + ox * 2;
    kap0[m] = ox + 6 * oy;
  }
  const int co = coh * 64 + wv * 16 + r16;
  const int bOff = kg * 256 + co;    // s16x8 slot within tap
  const float bias = b2[co];

  const f32x4 vzero = {0.f, 0.f, 0.f, 0.f};
  f32x4 acc[3];
#pragma unroll
  for (int m = 0; m < 3; ++m) acc[m] = vzero;

  const s16x8* wsv = (const s16x8*)wstg;

  for (int chunk = 0; chunk < 8; ++chunk) {
    __syncthreads();  // previous chunk fully consumed
    {
      const short* src = c1g + ((size_t)(img * 8 + chunk) * 384) * 64;
      for (int c = wv; c < 48; c += 4)
        stage16(src + c * 512 + lane * 8, &c1[c * 512]);
    }
    __syncthreads();  // vmcnt drain: chunk staged

    const size_t bb = (size_t)chunk * 81 * 2048 + bOff;
    s16x8 BHc = wsv[bb], BLc = wsv[bb + 1024];
    for (int ky = 0; ky < 9; ++ky) {
      const int rbase = ky * 20;
      const int kapky = 6 * (ky >> 1);
#pragma unroll
      for (int kx = 0; kx < 9; ++kx) {
        const int tt = ky * 9 + kx;
        s16x8 BHn, BLn;
        if (tt < 80) {
          const size_t nb = bb + (size_t)(tt + 1) * 2048;
          BHn = wsv[nb];
          BLn = wsv[nb + 1024];
        }
        s16x8 AH[3], AL[3];
#pragma unroll
        for (int m = 0; m < 3; ++m) {
          const int row = arow[m] + rbase + kx;
          const int kap = kap0[m] + (kx >> 1) + kapky;
          AH[m] = *(const s16x8*)&c1[row * 64 + (((kg + kap) & 7) << 3)];
          AL[m] = *(const s16x8*)&c1[row * 64 + (((kg + 4 + kap) & 7) << 3)];
        }
#pragma unroll
        for (int m = 0; m < 3; ++m)
          acc[m] = __builtin_amdgcn_mfma_f32_16x16x32_bf16(AH[m], BHc, acc[m], 0, 0, 0);
#pragma unroll
        for (int m = 0; m < 3; ++m)
          acc[m] = __builtin_amdgcn_mfma_f32_16x16x32_bf16(AL[m], BHc, acc[m], 0, 0, 0);
#pragma unroll
        for (int m = 0; m < 3; ++m)
          acc[m] = __builtin_amdgcn_mfma_f32_16x16x32_bf16(AH[m], BLc, acc[m], 0, 0, 0);
        BHc = BHn;
        BLc = BLn;
      }
    }
  }

  // store: D col = r16 (co), row = kg*4 + reg (pos)
#pragma unroll
  for (int m = 0; m < 3; ++m) {
#pragma unroll
    for (int jj = 0; jj < 4; ++jj) {
      const int pos = m * 16 + kg * 4 + jj;
      if (pos < 36) {
        const int n = (co & 31) * 36 + pos;
        xcaps[((size_t)img * 1152 + n) * 8 + (co >> 5)] = acc[m][jj] + bias;
      }
    }
  }
}

// ---------------- fused u_hat + routing: block per (o, image-pair) ----------------
__global__ __launch_bounds__(256) void routing_fused(const float* __restrict__ xcaps,
                                                     const float* __restrict__ W,
                                                     float* __restrict__ out) {
  const int o = blockIdx.x >> 7;     // 0..9
  const int bp = blockIdx.x & 127;   // image pair
  const int b0 = bp * 2, b1 = b0 + 1;
  const int t = threadIdx.x;
  const int k = t & 15, ng = t >> 4;
  __shared__ float xs0[1152 * 8];
  __shared__ float xs1[1152 * 8];
  __shared__ double redA[256], redB[256], redC[256], redD[256];
  __shared__ float s0s[16], s1s[16];
  __shared__ float sv0, sv1;
  __shared__ double f0, f1;

  {
    const float4* src0 = (const float4*)(xcaps + (size_t)b0 * 9216);
    const float4* src1 = (const float4*)(xcaps + (size_t)b1 * 9216);
    float4* d0 = (float4*)xs0;
    float4* d1 = (float4*)xs1;
    for (int i = t; i < 2304; i += 256) { d0[i] = src0[i]; d1[i] = src1[i]; }
  }
  __syncthreads();

  const int n0 = ng * 72;
  float u0[72], u1[72];
  const float* wp = W + ((size_t)(n0 * 10 + o) * 16 + k) * 8;
#pragma unroll
  for (int i = 0; i < 72; ++i) {
    const float* wq = wp + (size_t)i * 1280;
    const float4 wa = *(const float4*)wq;
    const float4 wb = *(const float4*)(wq + 4);
    const float4 xa0 = *(const float4*)&xs0[(n0 + i) * 8];
    const float4 xb0 = *(const float4*)&xs0[(n0 + i) * 8 + 4];
    const float4 xa1 = *(const float4*)&xs1[(n0 + i) * 8];
    const float4 xb1 = *(const float4*)&xs1[(n0 + i) * 8 + 4];
    float s0 = wa.x * xa0.x + wa.y * xa0.y + wa.z * xa0.z + wa.w * xa0.w
             + wb.x * xb0.x + wb.y * xb0.y + wb.z * xb0.z + wb.w * xb0.w;
    float s1 = wa.x * xa1.x + wa.y * xa1.y + wa.z * xa1.z + wa.w * xa1.w
             + wb.x * xb1.x + wb.y * xb1.y + wb.z * xb1.z + wb.w * xb1.w;
    u0[i] = s0;
    u1[i] = s1;
  }

  // ---- pass 1: uniform c = 1/1152 ----
  {
    double S0 = 0.0, S1 = 0.0;
#pragma unroll
    for (int i = 0; i < 72; ++i) { S0 += (double)u0[i]; S1 += (double)u1[i]; }
    redA[t] = S0; redB[t] = S1;
  }
  __syncthreads();
  if (t < 16) {
    double t0 = 0.0, t1 = 0.0;
#pragma unroll
    for (int g = 0; g < 16; ++g) { t0 += redA[g * 16 + t]; t1 += redB[g * 16 + t]; }
    s0s[t] = (float)(t0 * (double)(1.0f / 1152.0f));
    s1s[t] = (float)(t1 * (double)(1.0f / 1152.0f));
  }
  __syncthreads();
  if (t == 0) {
    double sn = 0.0;
#pragma unroll
    for (int kk = 0; kk < 16; ++kk) sn += (double)s0s[kk] * (double)s0s[kk];
    double f = sn / ((1.0 + sn) * sqrt(sn));
    double sv = 0.0;
#pragma unroll
    for (int kk = 0; kk < 16; ++kk) sv += (double)s0s[kk] * f;
    sv0 = (float)sv;
    sn = 0.0;
#pragma unroll
    for (int kk = 0; kk < 16; ++kk) sn += (double)s1s[kk] * (double)s1s[kk];
    f = sn / ((1.0 + sn) * sqrt(sn));
    sv = 0.0;
#pragma unroll
    for (int kk = 0; kk < 16; ++kk) sv += (double)s1s[kk] * f;
    sv1 = (float)sv;
  }
  __syncthreads();
  const float v10 = sv0, v11 = sv1;

  // ---- pass 2: logits u*sv1 ----
  {
    double E0 = 0.0, EU0 = 0.0, E1 = 0.0, EU1 = 0.0;
#pragma unroll
    for (int i = 0; i < 72; ++i) {
      const float e0 = expf(u0[i] * v10);
      E0 += (double)e0;
      EU0 += (double)e0 * (double)u0[i];
      const float e1 = expf(u1[i] * v11);
      E1 += (double)e1;
      EU1 += (double)e1 * (double)u1[i];
    }
    redA[t] = E0; redB[t] = EU0; redC[t] = E1; redD[t] = EU1;
  }
  __syncthreads();
  if (t < 16) {
    double e0 = 0.0, s0 = 0.0, e1 = 0.0, s1 = 0.0;
#pragma unroll
    for (int g = 0; g < 16; ++g) {
      e0 += redA[g * 16 + t]; s0 += redB[g * 16 + t];
      e1 += redC[g * 16 + t]; s1 += redD[g * 16 + t];
    }
    s0s[t] = (float)(s0 / e0);
    s1s[t] = (float)(s1 / e1);
  }
  __syncthreads();
  if (t == 0) {
    double sn = 0.0;
#pragma unroll
    for (int kk = 0; kk < 16; ++kk) sn += (double)s0s[kk] * (double)s0s[kk];
    double f = sn / ((1.0 + sn) * sqrt(sn));
    double sv = 0.0;
#pragma unroll
    for (int kk = 0; kk < 16; ++kk) sv += (double)s0s[kk] * f;
    sv0 = v10 + (float)sv;
    sn = 0.0;
#pragma unroll
    for (int kk = 0; kk < 16; ++kk) sn += (double)s1s[kk] * (double)s1s[kk];
    f = sn / ((1.0 + sn) * sqrt(sn));
    sv = 0.0;
#pragma unroll
    for (int kk = 0; kk < 16; ++kk) sv += (double)s1s[kk] * f;
    sv1 = v11 + (float)sv;
  }
  __syncthreads();
  const float v20 = sv0, v21 = sv1;

  // ---- pass 3 -> output ----
  {
    double E0 = 0.0, EU0 = 0.0, E1 = 0.0, EU1 = 0.0;
#pragma unroll
    for (int i = 0; i < 72; ++i) {
      const float e0 = expf(u0[i] * v20);
      E0 += (double)e0;
      EU0 += (double)e0 * (double)u0[i];
      const float e1 = expf(u1[i] * v21);
      E1 += (double)e1;
      EU1 += (double)e1 * (double)u1[i];
    }
    redA[t] = E0; redB[t] = EU0; redC[t] = E1; redD[t] = EU1;
  }
  __syncthreads();
  if (t < 16) {
    double e0 = 0.0, s0 = 0.0, e1 = 0.0, s1 = 0.0;
#pragma unroll
    for (int g = 0; g < 16; ++g) {
      e0 += redA[g * 16 + t]; s0 += redB[g * 16 + t];
      e1 += redC[g * 16 + t]; s1 += redD[g * 16 + t];
    }
    s0s[t] = (float)(s0 / e0);
    s1s[t] = (float)(s1 / e1);
  }
  __syncthreads();
  if (t == 0) {
    double sn = 0.0;
#pragma unroll
    for (int kk = 0; kk < 16; ++kk) sn += (double)s0s[kk] * (double)s0s[kk];
    f0 = sn / ((1.0 + sn) * sqrt(sn));
    sn = 0.0;
#pragma unroll
    for (int kk = 0; kk < 16; ++kk) sn += (double)s1s[kk] * (double)s1s[kk];
    f1 = sn / ((1.0 + sn) * sqrt(sn));
  }
  __syncthreads();
  if (t < 16) {
    out[b0 * 160 + o * 16 + t] = (float)((double)s0s[t] * f0);
    out[b1 * 160 + o * 16 + t] = (float)((double)s1s[t] * f1);
  }
}

extern "C" void kernel_launch(void* const* d_in, const int* in_sizes, int n_in,
                              void* d_out, int out_size, void* d_ws, size_t ws_size,
                              hipStream_t stream) {
  const float* data = (const float*)d_in[0];
  const float* w1   = (const float*)d_in[1];
  const float* b1   = (const float*)d_in[2];
  const float* w2   = (const float*)d_in[3];
  const float* b2   = (const float*)d_in[4];
  const float* W    = (const float*)d_in[5];
  float* out = (float*)d_out;

  short* wstg  = (short*)d_ws;               // 10,616,832 shorts (21.2 MB)
  short* c1g   = wstg + 10616832;            // 50,331,648 shorts (100.7 MB)
  float* xcaps = (float*)(c1g + 50331648);   //  2,359,296 floats (  9.4 MB)

  prep_all<<<3104, 256, 0, stream>>>(w2, (s16x8*)wstg, data, w1, b1, c1g);
  conv2_mfma<<<1024, 256, 0, stream>>>(c1g, wstg, b2, xcaps);
  routing_fused<<<1280, 256, 0, stream>>>(xcaps, W, out);
}

// Round 13
// 633.220 us; speedup vs baseline: 1.3414x; 1.0466x over previous
//
#include <hip/hip_runtime.h>
#include <hip/hip_bf16.h>
#include <cmath>

// CapsNet forward. conv2 = split-bf16 MFMA (3-product), kx-PARITY-SPLIT LDS:
//  c1 chunk staged as two half-buffers in ONE 24,576 B LDS region:
//    even-x rows (rE = y*10 + x/2, 190 rows) -> 45 even-kx taps,
//    odd-x rows  (rO = y*9  + x/2, 171 rows) -> 36 odd-kx taps.
//  Slot swizzle: hi at ((kg+r)&7), lo at ((kg+4+r)&7) within each 128B row ->
//  every 8-lane b128 group <=2-way (free). 4 barriers/chunk.
//  grid 1024 = coh(4) x img(256); 256 thr / 4 waves; N=16/wave; 9 MFMA/tap.
// ws: wstg 21.2 MB | c1g 96.5 MB | xcaps 9.4 MB = 127.1 MB

typedef float f32x4 __attribute__((ext_vector_type(4)));
typedef short s16x8 __attribute__((ext_vector_type(8)));
typedef unsigned int u32;

static __device__ __forceinline__ short f2bf(float x) {
  __hip_bfloat16 h = __float2bfloat16(x);
  return *reinterpret_cast<short*>(&h);
}
static __device__ __forceinline__ float bf2f(short s) {
  __hip_bfloat16 h;
  *reinterpret_cast<short*>(&h) = s;
  return __bfloat162float(h);
}
static __device__ __forceinline__ void stage16(const short* g, short* l) {
  __builtin_amdgcn_global_load_lds(
      (const __attribute__((address_space(1))) u32*)(const void*)g,
      (__attribute__((address_space(3))) u32*)(void*)l, 16, 0, 0);
}

// c1g chunk layout: even section 192 rows x 64 shorts | odd section 176 x 64.
#define CHUNK_SHORTS 23552  // (192+176)*64
#define ODD_OFS 12288       // 192*64

// ---------------- merged prep: w2->wstg  |  conv1->c1g ----------------
__global__ __launch_bounds__(256) void prep_all(
    const float* __restrict__ w2, s16x8* __restrict__ wstg,
    const float* __restrict__ data, const float* __restrict__ w1,
    const float* __restrict__ b1, short* __restrict__ c1g) {
  if (blockIdx.x < 2592) {
    const int gid = blockIdx.x * 256 + threadIdx.x;  // 663,552 = 648*1024
    const int T = gid >> 10;
    const int s = gid & 1023;
    const int kg = s >> 8, co = s & 255;
    const int chunk = T / 81, tap = T - chunk * 81;
    const float* src = w2 + ((size_t)co * 256 + chunk * 32 + kg * 8) * 81 + tap;
    s16x8 hi, lo;
#pragma unroll
    for (int i = 0; i < 8; ++i) {
      const float x = src[i * 81];
      const short h = f2bf(x);
      hi[i] = h;
      lo[i] = f2bf(x - bf2f(h));
    }
    wstg[(size_t)T * 2048 + s] = hi;
    wstg[(size_t)T * 2048 + 1024 + s] = lo;
    return;
  }
  // ---- conv1 -> c1g (512 blocks: img*2 + yh); y,x == 19 dead for conv2 ----
  const int cb = blockIdx.x - 2592;
  const int img = cb >> 1;
  const int yh = cb & 1;
  const int t = threadIdx.x;
  __shared__ float simg[19 * 36];
  for (int i = t; i < 19 * 28; i += 256) {
    const int r = i / 28, c = i % 28;
    if (yh * 10 + r < 28) simg[r * 36 + c] = data[img * 784 + (yh * 10 + r) * 28 + c];
  }
  __syncthreads();
  for (int task = t; task < 2560; task += 256) {
    const int ci = task & 255;
    const int yl = task >> 8;       // 0..9
    const int y = yh * 10 + yl;
    if (y >= 19) continue;          // dead row
    const float* wr = w1 + ci * 81;
    float acc[20];
    const float bz = b1[ci];
#pragma unroll
    for (int x = 0; x < 20; ++x) acc[x] = bz;
#pragma unroll
    for (int ky = 0; ky < 9; ++ky) {
      float rr[28];
#pragma unroll
      for (int q = 0; q < 7; ++q)
        *(float4*)&rr[q * 4] = *(const float4*)&simg[(yl + ky) * 36 + q * 4];
#pragma unroll
      for (int kx = 0; kx < 9; ++kx) {
        const float w = wr[ky * 9 + kx];
#pragma unroll
        for (int x = 0; x < 20; ++x) acc[x] = fmaf(w, rr[x + kx], acc[x]);
      }
    }
    const int chunk = ci >> 5, cil = ci & 31, kg = cil >> 3, il = cil & 7;
    short* cbase = c1g + (size_t)(img * 8 + chunk) * CHUNK_SHORTS;
#pragma unroll
    for (int x = 0; x < 19; ++x) {  // x==19 dead
      const int xh = x >> 1;
      const int r = (x & 1) ? (y * 9 + xh) : (y * 10 + xh);
      short* base = cbase + ((x & 1) ? ODD_OFS : 0);
      const float v = fmaxf(acc[x], 0.f);
      const short hi = f2bf(v);
      const short lo = f2bf(v - bf2f(hi));
      base[r * 64 + (((kg + r) & 7) << 3) + il] = hi;
      base[r * 64 + (((kg + 4 + r) & 7) << 3) + il] = lo;
    }
  }
}

// ---------------- conv2 via MFMA, parity-split 24,576 B LDS ----------------
__global__ __launch_bounds__(256) void conv2_mfma(
    const short* __restrict__ c1g, const short* __restrict__ wstg,
    const float* __restrict__ b2, float* __restrict__ xcaps) {
  const int t = threadIdx.x;
  const int coh = blockIdx.x >> 8;   // co-major: XCD-mates share a slice
  const int img = blockIdx.x & 255;
  const int lane = t & 63;
  const int wv = t >> 6;             // 0..3
  const int r16 = lane & 15;
  const int kg = lane >> 4;

  __shared__ short c1[12288];        // 24,576 B

  int arowE[3], arowO[3];
#pragma unroll
  for (int m = 0; m < 3; ++m) {
    int pos = m * 16 + r16;
    if (pos > 35) pos = 35;          // clamped: same-addr broadcast, discarded
    const int oy = pos / 6, ox = pos % 6;
    arowE[m] = oy * 20 + ox;         // rE = arowE + ky*10 + kxi
    arowO[m] = oy * 18 + ox;         // rO = arowO + ky*9  + kxi
  }
  const int co = coh * 64 + wv * 16 + r16;
  const int bOff = kg * 256 + co;    // s16x8 slot within tap
  const float bias = b2[co];

  const f32x4 vzero = {0.f, 0.f, 0.f, 0.f};
  f32x4 acc[3];
#pragma unroll
  for (int m = 0; m < 3; ++m) acc[m] = vzero;

  const s16x8* wsv = (const s16x8*)wstg;

  for (int chunk = 0; chunk < 8; ++chunk) {
    const short* src = c1g + (size_t)(img * 8 + chunk) * CHUNK_SHORTS;
    const size_t bb = (size_t)chunk * 81 * 2048 + bOff;

    // ==== EVEN pass: stage 24 units, taps kx = 2*kxi ====
    __syncthreads();  // prev contents consumed
    for (int c = wv; c < 24; c += 4)
      stage16(src + c * 512 + lane * 8, &c1[c * 512]);
    __syncthreads();  // staged
    {
      s16x8 BHc = wsv[bb], BLc = wsv[bb + 1024];  // tap 0
      for (int ky = 0; ky < 9; ++ky) {
#pragma unroll
        for (int kxi = 0; kxi < 5; ++kxi) {
          s16x8 BHn, BLn;
          if (!(ky == 8 && kxi == 4)) {
            const int nky = (kxi == 4) ? ky + 1 : ky;
            const int nkxi = (kxi == 4) ? 0 : kxi + 1;
            const size_t nb = bb + (size_t)(nky * 9 + 2 * nkxi) * 2048;
            BHn = wsv[nb];
            BLn = wsv[nb + 1024];
          }
          s16x8 AH[3], AL[3];
#pragma unroll
          for (int m = 0; m < 3; ++m) {
            const int r = arowE[m] + ky * 10 + kxi;
            AH[m] = *(const s16x8*)&c1[r * 64 + (((kg + r) & 7) << 3)];
            AL[m] = *(const s16x8*)&c1[r * 64 + (((kg + 4 + r) & 7) << 3)];
          }
#pragma unroll
          for (int m = 0; m < 3; ++m)
            acc[m] = __builtin_amdgcn_mfma_f32_16x16x32_bf16(AH[m], BHc, acc[m], 0, 0, 0);
#pragma unroll
          for (int m = 0; m < 3; ++m)
            acc[m] = __builtin_amdgcn_mfma_f32_16x16x32_bf16(AL[m], BHc, acc[m], 0, 0, 0);
#pragma unroll
          for (int m = 0; m < 3; ++m)
            acc[m] = __builtin_amdgcn_mfma_f32_16x16x32_bf16(AH[m], BLc, acc[m], 0, 0, 0);
          BHc = BHn;
          BLc = BLn;
        }
      }
    }

    // ==== ODD pass: stage 22 units, taps kx = 2*kxi+1 ====
    __syncthreads();  // even contents consumed
    for (int c = wv; c < 22; c += 4)
      stage16(src + ODD_OFS + c * 512 + lane * 8, &c1[c * 512]);
    __syncthreads();  // staged
    {
      s16x8 BHc = wsv[bb + 2048], BLc = wsv[bb + 2048 + 1024];  // tap 1
      for (int ky = 0; ky < 9; ++ky) {
#pragma unroll
        for (int kxi = 0; kxi < 4; ++kxi) {
          s16x8 BHn, BLn;
          if (!(ky == 8 && kxi == 3)) {
            const int nky = (kxi == 3) ? ky + 1 : ky;
            const int nkxi = (kxi == 3) ? 0 : kxi + 1;
            const size_t nb = bb + (size_t)(nky * 9 + 2 * nkxi + 1) * 2048;
            BHn = wsv[nb];
            BLn = wsv[nb + 1024];
          }
          s16x8 AH[3], AL[3];
#pragma unroll
          for (int m = 0; m < 3; ++m) {
            const int r = arowO[m] + ky * 9 + kxi;
            AH[m] = *(const s16x8*)&c1[r * 64 + (((kg + r) & 7) << 3)];
            AL[m] = *(const s16x8*)&c1[r * 64 + (((kg + 4 + r) & 7) << 3)];
          }
#pragma unroll
          for (int m = 0; m < 3; ++m)
            acc[m] = __builtin_amdgcn_mfma_f32_16x16x32_bf16(AH[m], BHc, acc[m], 0, 0, 0);
#pragma unroll
          for (int m = 0; m < 3; ++m)
            acc[m] = __builtin_amdgcn_mfma_f32_16x16x32_bf16(AL[m], BHc, acc[m], 0, 0, 0);
#pragma unroll
          for (int m = 0; m < 3; ++m)
            acc[m] = __builtin_amdgcn_mfma_f32_16x16x32_bf16(AH[m], BLc, acc[m], 0, 0, 0);
          BHc = BHn;
          BLc = BLn;
        }
      }
    }
  }

  // store: D col = r16 (co), row = kg*4 + reg (pos)
#pragma unroll
  for (int m = 0; m < 3; ++m) {
#pragma unroll
    for (int jj = 0; jj < 4; ++jj) {
      const int pos = m * 16 + kg * 4 + jj;
      if (pos < 36) {
        const int n = (co & 31) * 36 + pos;
        xcaps[((size_t)img * 1152 + n) * 8 + (co >> 5)] = acc[m][jj] + bias;
      }
    }
  }
}

// ---------------- fused u_hat + routing: block per (o, image-pair) ----------------
__global__ __launch_bounds__(256) void routing_fused(const float* __restrict__ xcaps,
                                                     const float* __restrict__ W,
                                                     float* __restrict__ out) {
  const int o = blockIdx.x >> 7;     // 0..9
  const int bp = blockIdx.x & 127;   // image pair
  const int b0 = bp * 2, b1 = b0 + 1;
  const int t = threadIdx.x;
  const int k = t & 15, ng = t >> 4;
  __shared__ float xs0[1152 * 8];
  __shared__ float xs1[1152 * 8];
  __shared__ double redA[256], redB[256], redC[256], redD[256];
  __shared__ float s0s[16], s1s[16];
  __shared__ float sv0, sv1;
  __shared__ double f0, f1;

  {
    const float4* src0 = (const float4*)(xcaps + (size_t)b0 * 9216);
    const float4* src1 = (const float4*)(xcaps + (size_t)b1 * 9216);
    float4* d0 = (float4*)xs0;
    float4* d1 = (float4*)xs1;
    for (int i = t; i < 2304; i += 256) { d0[i] = src0[i]; d1[i] = src1[i]; }
  }
  __syncthreads();

  const int n0 = ng * 72;
  float u0[72], u1[72];
  const float* wp = W + ((size_t)(n0 * 10 + o) * 16 + k) * 8;
#pragma unroll
  for (int i = 0; i < 72; ++i) {
    const float* wq = wp + (size_t)i * 1280;
    const float4 wa = *(const float4*)wq;
    const float4 wb = *(const float4*)(wq + 4);
    const float4 xa0 = *(const float4*)&xs0[(n0 + i) * 8];
    const float4 xb0 = *(const float4*)&xs0[(n0 + i) * 8 + 4];
    const float4 xa1 = *(const float4*)&xs1[(n0 + i) * 8];
    const float4 xb1 = *(const float4*)&xs1[(n0 + i) * 8 + 4];
    float s0 = wa.x * xa0.x + wa.y * xa0.y + wa.z * xa0.z + wa.w * xa0.w
             + wb.x * xb0.x + wb.y * xb0.y + wb.z * xb0.z + wb.w * xb0.w;
    float s1 = wa.x * xa1.x + wa.y * xa1.y + wa.z * xa1.z + wa.w * xa1.w
             + wb.x * xb1.x + wb.y * xb1.y + wb.z * xb1.z + wb.w * xb1.w;
    u0[i] = s0;
    u1[i] = s1;
  }

  // ---- pass 1: uniform c = 1/1152 ----
  {
    double S0 = 0.0, S1 = 0.0;
#pragma unroll
    for (int i = 0; i < 72; ++i) { S0 += (double)u0[i]; S1 += (double)u1[i]; }
    redA[t] = S0; redB[t] = S1;
  }
  __syncthreads();
  if (t < 16) {
    double t0 = 0.0, t1 = 0.0;
#pragma unroll
    for (int g = 0; g < 16; ++g) { t0 += redA[g * 16 + t]; t1 += redB[g * 16 + t]; }
    s0s[t] = (float)(t0 * (double)(1.0f / 1152.0f));
    s1s[t] = (float)(t1 * (double)(1.0f / 1152.0f));
  }
  __syncthreads();
  if (t == 0) {
    double sn = 0.0;
#pragma unroll
    for (int kk = 0; kk < 16; ++kk) sn += (double)s0s[kk] * (double)s0s[kk];
    double f = sn / ((1.0 + sn) * sqrt(sn));
    double sv = 0.0;
#pragma unroll
    for (int kk = 0; kk < 16; ++kk) sv += (double)s0s[kk] * f;
    sv0 = (float)sv;
    sn = 0.0;
#pragma unroll
    for (int kk = 0; kk < 16; ++kk) sn += (double)s1s[kk] * (double)s1s[kk];
    f = sn / ((1.0 + sn) * sqrt(sn));
    sv = 0.0;
#pragma unroll
    for (int kk = 0; kk < 16; ++kk) sv += (double)s1s[kk] * f;
    sv1 = (float)sv;
  }
  __syncthreads();
  const float v10 = sv0, v11 = sv1;

  // ---- pass 2: logits u*sv1 ----
  {
    double E0 = 0.0, EU0 = 0.0, E1 = 0.0, EU1 = 0.0;
#pragma unroll
    for (int i = 0; i < 72; ++i) {
      const float e0 = expf(u0[i] * v10);
      E0 += (double)e0;
      EU0 += (double)e0 * (double)u0[i];
      const float e1 = expf(u1[i] * v11);
      E1 += (double)e1;
      EU1 += (double)e1 * (double)u1[i];
    }
    redA[t] = E0; redB[t] = EU0; redC[t] = E1; redD[t] = EU1;
  }
  __syncthreads();
  if (t < 16) {
    double e0 = 0.0, s0 = 0.0, e1 = 0.0, s1 = 0.0;
#pragma unroll
    for (int g = 0; g < 16; ++g) {
      e0 += redA[g * 16 + t]; s0 += redB[g * 16 + t];
      e1 += redC[g * 16 + t]; s1 += redD[g * 16 + t];
    }
    s0s[t] = (float)(s0 / e0);
    s1s[t] = (float)(s1 / e1);
  }
  __syncthreads();
  if (t == 0) {
    double sn = 0.0;
#pragma unroll
    for (int kk = 0; kk < 16; ++kk) sn += (double)s0s[kk] * (double)s0s[kk];
    double f = sn / ((1.0 + sn) * sqrt(sn));
    double sv = 0.0;
#pragma unroll
    for (int kk = 0; kk < 16; ++kk) sv += (double)s0s[kk] * f;
    sv0 = v10 + (float)sv;
    sn = 0.0;
#pragma unroll
    for (int kk = 0; kk < 16; ++kk) sn += (double)s1s[kk] * (double)s1s[kk];
    f = sn / ((1.0 + sn) * sqrt(sn));
    sv = 0.0;
#pragma unroll
    for (int kk = 0; kk < 16; ++kk) sv += (double)s1s[kk] * f;
    sv1 = v11 + (float)sv;
  }
  __syncthreads();
  const float v20 = sv0, v21 = sv1;

  // ---- pass 3 -> output ----
  {
    double E0 = 0.0, EU0 = 0.0, E1 = 0.0, EU1 = 0.0;
#pragma unroll
    for (int i = 0; i < 72; ++i) {
      const float e0 = expf(u0[i] * v20);
      E0 += (double)e0;
      EU0 += (double)e0 * (double)u0[i];
      const float e1 = expf(u1[i] * v21);
      E1 += (double)e1;
      EU1 += (double)e1 * (double)u1[i];
    }
    redA[t] = E0; redB[t] = EU0; redC[t] = E1; redD[t] = EU1;
  }
  __syncthreads();
  if (t < 16) {
    double e0 = 0.0, s0 = 0.0, e1 = 0.0, s1 = 0.0;
#pragma unroll
    for (int g = 0; g < 16; ++g) {
      e0 += redA[g * 16 + t]; s0 += redB[g * 16 + t];
      e1 += redC[g * 16 + t]; s1 += redD[g * 16 + t];
    }
    s0s[t] = (float)(s0 / e0);
    s1s[t] = (float)(s1 / e1);
  }
  __syncthreads();
  if (t == 0) {
    double sn = 0.0;
#pragma unroll
    for (int kk = 0; kk < 16; ++kk) sn += (double)s0s[kk] * (double)s0s[kk];
    f0 = sn / ((1.0 + sn) * sqrt(sn));
    sn = 0.0;
#pragma unroll
    for (int kk = 0; kk < 16; ++kk) sn += (double)s1s[kk] * (double)s1s[kk];
    f1 = sn / ((1.0 + sn) * sqrt(sn));
  }
  __syncthreads();
  if (t < 16) {
    out[b0 * 160 + o * 16 + t] = (float)((double)s0s[t] * f0);
    out[b1 * 160 + o * 16 + t] = (float)((double)s1s[t] * f1);
  }
}

extern "C" void kernel_launch(void* const* d_in, const int* in_sizes, int n_in,
                              void* d_out, int out_size, void* d_ws, size_t ws_size,
                              hipStream_t stream) {
  const float* data = (const float*)d_in[0];
  const float* w1   = (const float*)d_in[1];
  const float* b1   = (const float*)d_in[2];
  const float* w2   = (const float*)d_in[3];
  const float* b2   = (const float*)d_in[4];
  const float* W    = (const float*)d_in[5];
  float* out = (float*)d_out;

  short* wstg  = (short*)d_ws;               // 10,616,832 shorts (21.2 MB)
  short* c1g   = wstg + 10616832;            // 256*8*23,552 = 48,234,496 shorts
  float* xcaps = (float*)(c1g + 48234496);   //  2,359,296 floats (9.4 MB)

  prep_all<<<3104, 256, 0, stream>>>(w2, (s16x8*)wstg, data, w1, b1, c1g);
  conv2_mfma<<<1024, 256, 0, stream>>>(c1g, wstg, b2, xcaps);
  routing_fused<<<1280, 256, 0, stream>>>(xcaps, W, out);
}

// Round 14
// 578.686 us; speedup vs baseline: 1.4678x; 1.0942x over previous
//
#include <hip/hip_runtime.h>
#include <hip/hip_bf16.h>
#include <cmath>

// CapsNet forward. conv2 = split-bf16 MFMA (3-product), kx-parity-split LDS
// (24,576 B), N=32/wave, K-SPLIT x2 with SEPARATE OUTPUT PARTS (no atomics):
//  grid 1024 = img(256) x ksp(2) x coh(2) via xcd=bid&7; block does 4 chunks;
//  each wave: 2 co-tiles (N=32), 3 M-tiles, 18 MFMA/tap;
//  part ksp written with plain stores to xcaps[ksp]; routing sums the parts.
// ws: wstg 21.2 | c1g 96.5 | xcaps0 9.4 | xcaps1 9.4 = 146.5 MB... (136.5 MB)

typedef float f32x4 __attribute__((ext_vector_type(4)));
typedef short s16x8 __attribute__((ext_vector_type(8)));
typedef unsigned int u32;

static __device__ __forceinline__ short f2bf(float x) {
  __hip_bfloat16 h = __float2bfloat16(x);
  return *reinterpret_cast<short*>(&h);
}
static __device__ __forceinline__ float bf2f(short s) {
  __hip_bfloat16 h;
  *reinterpret_cast<short*>(&h) = s;
  return __bfloat162float(h);
}
static __device__ __forceinline__ void stage16(const short* g, short* l) {
  __builtin_amdgcn_global_load_lds(
      (const __attribute__((address_space(1))) u32*)(const void*)g,
      (__attribute__((address_space(3))) u32*)(void*)l, 16, 0, 0);
}

// c1g chunk layout: even section 192 rows x 64 shorts | odd section 176 x 64.
#define CHUNK_SHORTS 23552  // (192+176)*64
#define ODD_OFS 12288       // 192*64

// ---------------- merged prep: w2->wstg  |  conv1->c1g ----------------
__global__ __launch_bounds__(256) void prep_all(
    const float* __restrict__ w2, s16x8* __restrict__ wstg,
    const float* __restrict__ data, const float* __restrict__ w1,
    const float* __restrict__ b1, short* __restrict__ c1g) {
  if (blockIdx.x < 2592) {
    const int gid = blockIdx.x * 256 + threadIdx.x;  // 663,552 = 648*1024
    const int T = gid >> 10;
    const int s = gid & 1023;
    const int kg = s >> 8, co = s & 255;
    const int chunk = T / 81, tap = T - chunk * 81;
    const float* src = w2 + ((size_t)co * 256 + chunk * 32 + kg * 8) * 81 + tap;
    s16x8 hi, lo;
#pragma unroll
    for (int i = 0; i < 8; ++i) {
      const float x = src[i * 81];
      const short h = f2bf(x);
      hi[i] = h;
      lo[i] = f2bf(x - bf2f(h));
    }
    wstg[(size_t)T * 2048 + s] = hi;
    wstg[(size_t)T * 2048 + 1024 + s] = lo;
    return;
  }
  // ---- conv1 -> c1g (512 blocks: img*2 + yh); y,x == 19 dead for conv2 ----
  const int cb = blockIdx.x - 2592;
  const int img = cb >> 1;
  const int yh = cb & 1;
  const int t = threadIdx.x;
  __shared__ float simg[19 * 36];
  for (int i = t; i < 19 * 28; i += 256) {
    const int r = i / 28, c = i % 28;
    if (yh * 10 + r < 28) simg[r * 36 + c] = data[img * 784 + (yh * 10 + r) * 28 + c];
  }
  __syncthreads();
  for (int task = t; task < 2560; task += 256) {
    const int ci = task & 255;
    const int yl = task >> 8;       // 0..9
    const int y = yh * 10 + yl;
    if (y >= 19) continue;          // dead row
    const float* wr = w1 + ci * 81;
    float acc[20];
    const float bz = b1[ci];
#pragma unroll
    for (int x = 0; x < 20; ++x) acc[x] = bz;
#pragma unroll
    for (int ky = 0; ky < 9; ++ky) {
      float rr[28];
#pragma unroll
      for (int q = 0; q < 7; ++q)
        *(float4*)&rr[q * 4] = *(const float4*)&simg[(yl + ky) * 36 + q * 4];
#pragma unroll
      for (int kx = 0; kx < 9; ++kx) {
        const float w = wr[ky * 9 + kx];
#pragma unroll
        for (int x = 0; x < 20; ++x) acc[x] = fmaf(w, rr[x + kx], acc[x]);
      }
    }
    const int chunk = ci >> 5, cil = ci & 31, kg = cil >> 3, il = cil & 7;
    short* cbase = c1g + (size_t)(img * 8 + chunk) * CHUNK_SHORTS;
#pragma unroll
    for (int x = 0; x < 19; ++x) {  // x==19 dead
      const int xh = x >> 1;
      const int r = (x & 1) ? (y * 9 + xh) : (y * 10 + xh);
      short* base = cbase + ((x & 1) ? ODD_OFS : 0);
      const float v = fmaxf(acc[x], 0.f);
      const short hi = f2bf(v);
      const short lo = f2bf(v - bf2f(hi));
      base[r * 64 + (((kg + r) & 7) << 3) + il] = hi;
      base[r * 64 + (((kg + 4 + r) & 7) << 3) + il] = lo;
    }
  }
}

// ---------------- conv2 via MFMA, N=32/wave, K-split parts ----------------
__global__ __launch_bounds__(256) void conv2_mfma(
    const short* __restrict__ c1g, const short* __restrict__ wstg,
    const float* __restrict__ b2, float* __restrict__ xcaps0,
    float* __restrict__ xcaps1) {
  const int t = threadIdx.x;
  const int bid = blockIdx.x;        // 1024
  const int xcd = bid & 7;
  const int ksp = xcd & 1;           // K half (chunks ksp*4 .. +4)
  const int coh = (xcd >> 1) & 1;    // co half
  const int img = (bid >> 3) * 2 + (xcd >> 2);
  const int lane = t & 63;
  const int wv = t >> 6;             // 0..3
  const int r16 = lane & 15;
  const int kg = lane >> 4;

  __shared__ short c1[12288];        // 24,576 B

  int arowE[3], arowO[3];
#pragma unroll
  for (int m = 0; m < 3; ++m) {
    int pos = m * 16 + r16;
    if (pos > 35) pos = 35;          // clamped: same-addr broadcast, discarded
    const int oy = pos / 6, ox = pos % 6;
    arowE[m] = oy * 20 + ox;         // rE = arowE + ky*10 + kxi
    arowO[m] = oy * 18 + ox;         // rO = arowO + ky*9  + kxi
  }
  int bOff[2], con[2];
  float bias[2];
#pragma unroll
  for (int j = 0; j < 2; ++j) {
    const int co = coh * 128 + wv * 32 + j * 16 + r16;
    con[j] = co;
    bOff[j] = kg * 256 + co;         // s16x8 slot within tap
    bias[j] = (ksp == 0) ? b2[co] : 0.f;
  }
  float* xcp = (ksp == 0) ? xcaps0 : xcaps1;

  const f32x4 vzero = {0.f, 0.f, 0.f, 0.f};
  f32x4 acc[3][2];
#pragma unroll
  for (int m = 0; m < 3; ++m)
#pragma unroll
    for (int j = 0; j < 2; ++j) acc[m][j] = vzero;

  const s16x8* wsv = (const s16x8*)wstg;

  for (int cc = 0; cc < 4; ++cc) {
    const int chunk = ksp * 4 + cc;
    const short* src = c1g + (size_t)(img * 8 + chunk) * CHUNK_SHORTS;
    const size_t bb = (size_t)chunk * 81 * 2048;

    // ==== EVEN pass: stage 24 units, taps kx = 2*kxi ====
    __syncthreads();  // prev contents consumed
    for (int c = wv; c < 24; c += 4)
      stage16(src + c * 512 + lane * 8, &c1[c * 512]);
    __syncthreads();  // staged
    {
      s16x8 BHc[2], BLc[2];
#pragma unroll
      for (int j = 0; j < 2; ++j) {
        BHc[j] = wsv[bb + bOff[j]];
        BLc[j] = wsv[bb + bOff[j] + 1024];
      }
      for (int ky = 0; ky < 9; ++ky) {
#pragma unroll
        for (int kxi = 0; kxi < 5; ++kxi) {
          s16x8 BHn[2], BLn[2];
          if (!(ky == 8 && kxi == 4)) {
            const int nky = (kxi == 4) ? ky + 1 : ky;
            const int nkxi = (kxi == 4) ? 0 : kxi + 1;
            const size_t nb = bb + (size_t)(nky * 9 + 2 * nkxi) * 2048;
#pragma unroll
            for (int j = 0; j < 2; ++j) {
              BHn[j] = wsv[nb + bOff[j]];
              BLn[j] = wsv[nb + bOff[j] + 1024];
            }
          }
          s16x8 AH[3], AL[3];
#pragma unroll
          for (int m = 0; m < 3; ++m) {
            const int r = arowE[m] + ky * 10 + kxi;
            AH[m] = *(const s16x8*)&c1[r * 64 + (((kg + r) & 7) << 3)];
            AL[m] = *(const s16x8*)&c1[r * 64 + (((kg + 4 + r) & 7) << 3)];
          }
#pragma unroll
          for (int m = 0; m < 3; ++m)
#pragma unroll
            for (int j = 0; j < 2; ++j)
              acc[m][j] = __builtin_amdgcn_mfma_f32_16x16x32_bf16(AH[m], BHc[j], acc[m][j], 0, 0, 0);
#pragma unroll
          for (int m = 0; m < 3; ++m)
#pragma unroll
            for (int j = 0; j < 2; ++j)
              acc[m][j] = __builtin_amdgcn_mfma_f32_16x16x32_bf16(AL[m], BHc[j], acc[m][j], 0, 0, 0);
#pragma unroll
          for (int m = 0; m < 3; ++m)
#pragma unroll
            for (int j = 0; j < 2; ++j)
              acc[m][j] = __builtin_amdgcn_mfma_f32_16x16x32_bf16(AH[m], BLc[j], acc[m][j], 0, 0, 0);
#pragma unroll
          for (int j = 0; j < 2; ++j) { BHc[j] = BHn[j]; BLc[j] = BLn[j]; }
        }
      }
    }

    // ==== ODD pass: stage 22 units, taps kx = 2*kxi+1 ====
    __syncthreads();  // even contents consumed
    for (int c = wv; c < 22; c += 4)
      stage16(src + ODD_OFS + c * 512 + lane * 8, &c1[c * 512]);
    __syncthreads();  // staged
    {
      s16x8 BHc[2], BLc[2];
#pragma unroll
      for (int j = 0; j < 2; ++j) {
        BHc[j] = wsv[bb + 2048 + bOff[j]];
        BLc[j] = wsv[bb + 2048 + bOff[j] + 1024];
      }
      for (int ky = 0; ky < 9; ++ky) {
#pragma unroll
        for (int kxi = 0; kxi < 4; ++kxi) {
          s16x8 BHn[2], BLn[2];
          if (!(ky == 8 && kxi == 3)) {
            const int nky = (kxi == 3) ? ky + 1 : ky;
            const int nkxi = (kxi == 3) ? 0 : kxi + 1;
            const size_t nb = bb + (size_t)(nky * 9 + 2 * nkxi + 1) * 2048;
#pragma unroll
            for (int j = 0; j < 2; ++j) {
              BHn[j] = wsv[nb + bOff[j]];
              BLn[j] = wsv[nb + bOff[j] + 1024];
            }
          }
          s16x8 AH[3], AL[3];
#pragma unroll
          for (int m = 0; m < 3; ++m) {
            const int r = arowO[m] + ky * 9 + kxi;
            AH[m] = *(const s16x8*)&c1[r * 64 + (((kg + r) & 7) << 3)];
            AL[m] = *(const s16x8*)&c1[r * 64 + (((kg + 4 + r) & 7) << 3)];
          }
#pragma unroll
          for (int m = 0; m < 3; ++m)
#pragma unroll
            for (int j = 0; j < 2; ++j)
              acc[m][j] = __builtin_amdgcn_mfma_f32_16x16x32_bf16(AH[m], BHc[j], acc[m][j], 0, 0, 0);
#pragma unroll
          for (int m = 0; m < 3; ++m)
#pragma unroll
            for (int j = 0; j < 2; ++j)
              acc[m][j] = __builtin_amdgcn_mfma_f32_16x16x32_bf16(AL[m], BHc[j], acc[m][j], 0, 0, 0);
#pragma unroll
          for (int m = 0; m < 3; ++m)
#pragma unroll
            for (int j = 0; j < 2; ++j)
              acc[m][j] = __builtin_amdgcn_mfma_f32_16x16x32_bf16(AH[m], BLc[j], acc[m][j], 0, 0, 0);
#pragma unroll
          for (int j = 0; j < 2; ++j) { BHc[j] = BHn[j]; BLc[j] = BLn[j]; }
        }
      }
    }
  }

  // store partial: D col = r16 (co), row = kg*4 + reg (pos)
#pragma unroll
  for (int m = 0; m < 3; ++m) {
#pragma unroll
    for (int jj = 0; jj < 4; ++jj) {
      const int pos = m * 16 + kg * 4 + jj;
      if (pos < 36) {
#pragma unroll
        for (int j = 0; j < 2; ++j) {
          const int co = con[j];
          const int n = (co & 31) * 36 + pos;
          xcp[((size_t)img * 1152 + n) * 8 + (co >> 5)] = acc[m][j][jj] + bias[j];
        }
      }
    }
  }
}

// ---------------- fused u_hat + routing: block per (o, image-pair) ----------------
__global__ __launch_bounds__(256) void routing_fused(const float* __restrict__ xcaps0,
                                                     const float* __restrict__ xcaps1,
                                                     const float* __restrict__ W,
                                                     float* __restrict__ out) {
  const int o = blockIdx.x >> 7;     // 0..9
  const int bp = blockIdx.x & 127;   // image pair
  const int b0 = bp * 2, b1 = b0 + 1;
  const int t = threadIdx.x;
  const int k = t & 15, ng = t >> 4;
  __shared__ float xs0[1152 * 8];
  __shared__ float xs1[1152 * 8];
  __shared__ double redA[256], redB[256], redC[256], redD[256];
  __shared__ float s0s[16], s1s[16];
  __shared__ float sv0, sv1;
  __shared__ double f0, f1;

  {
    const float4* p00 = (const float4*)(xcaps0 + (size_t)b0 * 9216);
    const float4* p01 = (const float4*)(xcaps1 + (size_t)b0 * 9216);
    const float4* p10 = (const float4*)(xcaps0 + (size_t)b1 * 9216);
    const float4* p11 = (const float4*)(xcaps1 + (size_t)b1 * 9216);
    float4* d0 = (float4*)xs0;
    float4* d1 = (float4*)xs1;
    for (int i = t; i < 2304; i += 256) {
      float4 a = p00[i], b = p01[i];
      float4 c = p10[i], d = p11[i];
      float4 s0, s1;
      s0.x = a.x + b.x; s0.y = a.y + b.y; s0.z = a.z + b.z; s0.w = a.w + b.w;
      s1.x = c.x + d.x; s1.y = c.y + d.y; s1.z = c.z + d.z; s1.w = c.w + d.w;
      d0[i] = s0;
      d1[i] = s1;
    }
  }
  __syncthreads();

  const int n0 = ng * 72;
  float u0[72], u1[72];
  const float* wp = W + ((size_t)(n0 * 10 + o) * 16 + k) * 8;
#pragma unroll
  for (int i = 0; i < 72; ++i) {
    const float* wq = wp + (size_t)i * 1280;
    const float4 wa = *(const float4*)wq;
    const float4 wb = *(const float4*)(wq + 4);
    const float4 xa0 = *(const float4*)&xs0[(n0 + i) * 8];
    const float4 xb0 = *(const float4*)&xs0[(n0 + i) * 8 + 4];
    const float4 xa1 = *(const float4*)&xs1[(n0 + i) * 8];
    const float4 xb1 = *(const float4*)&xs1[(n0 + i) * 8 + 4];
    float s0 = wa.x * xa0.x + wa.y * xa0.y + wa.z * xa0.z + wa.w * xa0.w
             + wb.x * xb0.x + wb.y * xb0.y + wb.z * xb0.z + wb.w * xb0.w;
    float s1 = wa.x * xa1.x + wa.y * xa1.y + wa.z * xa1.z + wa.w * xa1.w
             + wb.x * xb1.x + wb.y * xb1.y + wb.z * xb1.z + wb.w * xb1.w;
    u0[i] = s0;
    u1[i] = s1;
  }

  // ---- pass 1: uniform c = 1/1152 ----
  {
    double S0 = 0.0, S1 = 0.0;
#pragma unroll
    for (int i = 0; i < 72; ++i) { S0 += (double)u0[i]; S1 += (double)u1[i]; }
    redA[t] = S0; redB[t] = S1;
  }
  __syncthreads();
  if (t < 16) {
    double t0 = 0.0, t1 = 0.0;
#pragma unroll
    for (int g = 0; g < 16; ++g) { t0 += redA[g * 16 + t]; t1 += redB[g * 16 + t]; }
    s0s[t] = (float)(t0 * (double)(1.0f / 1152.0f));
    s1s[t] = (float)(t1 * (double)(1.0f / 1152.0f));
  }
  __syncthreads();
  if (t == 0) {
    double sn = 0.0;
#pragma unroll
    for (int kk = 0; kk < 16; ++kk) sn += (double)s0s[kk] * (double)s0s[kk];
    double f = sn / ((1.0 + sn) * sqrt(sn));
    double sv = 0.0;
#pragma unroll
    for (int kk = 0; kk < 16; ++kk) sv += (double)s0s[kk] * f;
    sv0 = (float)sv;
    sn = 0.0;
#pragma unroll
    for (int kk = 0; kk < 16; ++kk) sn += (double)s1s[kk] * (double)s1s[kk];
    f = sn / ((1.0 + sn) * sqrt(sn));
    sv = 0.0;
#pragma unroll
    for (int kk = 0; kk < 16; ++kk) sv += (double)s1s[kk] * f;
    sv1 = (float)sv;
  }
  __syncthreads();
  const float v10 = sv0, v11 = sv1;

  // ---- pass 2: logits u*sv1 ----
  {
    double E0 = 0.0, EU0 = 0.0, E1 = 0.0, EU1 = 0.0;
#pragma unroll
    for (int i = 0; i < 72; ++i) {
      const float e0 = expf(u0[i] * v10);
      E0 += (double)e0;
      EU0 += (double)e0 * (double)u0[i];
      const float e1 = expf(u1[i] * v11);
      E1 += (double)e1;
      EU1 += (double)e1 * (double)u1[i];
    }
    redA[t] = E0; redB[t] = EU0; redC[t] = E1; redD[t] = EU1;
  }
  __syncthreads();
  if (t < 16) {
    double e0 = 0.0, s0 = 0.0, e1 = 0.0, s1 = 0.0;
#pragma unroll
    for (int g = 0; g < 16; ++g) {
      e0 += redA[g * 16 + t]; s0 += redB[g * 16 + t];
      e1 += redC[g * 16 + t]; s1 += redD[g * 16 + t];
    }
    s0s[t] = (float)(s0 / e0);
    s1s[t] = (float)(s1 / e1);
  }
  __syncthreads();
  if (t == 0) {
    double sn = 0.0;
#pragma unroll
    for (int kk = 0; kk < 16; ++kk) sn += (double)s0s[kk] * (double)s0s[kk];
    double f = sn / ((1.0 + sn) * sqrt(sn));
    double sv = 0.0;
#pragma unroll
    for (int kk = 0; kk < 16; ++kk) sv += (double)s0s[kk] * f;
    sv0 = v10 + (float)sv;
    sn = 0.0;
#pragma unroll
    for (int kk = 0; kk < 16; ++kk) sn += (double)s1s[kk] * (double)s1s[kk];
    f = sn / ((1.0 + sn) * sqrt(sn));
    sv = 0.0;
#pragma unroll
    for (int kk = 0; kk < 16; ++kk) sv += (double)s1s[kk] * f;
    sv1 = v11 + (float)sv;
  }
  __syncthreads();
  const float v20 = sv0, v21 = sv1;

  // ---- pass 3 -> output ----
  {
    double E0 = 0.0, EU0 = 0.0, E1 = 0.0, EU1 = 0.0;
#pragma unroll
    for (int i = 0; i < 72; ++i) {
      const float e0 = expf(u0[i] * v20);
      E0 += (double)e0;
      EU0 += (double)e0 * (double)u0[i];
      const float e1 = expf(u1[i] * v21);
      E1 += (double)e1;
      EU1 += (double)e1 * (double)u1[i];
    }
    redA[t] = E0; redB[t] = EU0; redC[t] = E1; redD[t] = EU1;
  }
  __syncthreads();
  if (t < 16) {
    double e0 = 0.0, s0 = 0.0, e1 = 0.0, s1 = 0.0;
#pragma unroll
    for (int g = 0; g < 16; ++g) {
      e0 += redA[g * 16 + t]; s0 += redB[g * 16 + t];
      e1 += redC[g * 16 + t]; s1 += redD[g * 16 + t];
    }
    s0s[t] = (float)(s0 / e0);
    s1s[t] = (float)(s1 / e1);
  }
  __syncthreads();
  if (t == 0) {
    double sn = 0.0;
#pragma unroll
    for (int kk = 0; kk < 16; ++kk) sn += (double)s0s[kk] * (double)s0s[kk];
    f0 = sn / ((1.0 + sn) * sqrt(sn));
    sn = 0.0;
#pragma unroll
    for (int kk = 0; kk < 16; ++kk) sn += (double)s1s[kk] * (double)s1s[kk];
    f1 = sn / ((1.0 + sn) * sqrt(sn));
  }
  __syncthreads();
  if (t < 16) {
    out[b0 * 160 + o * 16 + t] = (float)((double)s0s[t] * f0);
    out[b1 * 160 + o * 16 + t] = (float)((double)s1s[t] * f1);
  }
}

extern "C" void kernel_launch(void* const* d_in, const int* in_sizes, int n_in,
                              void* d_out, int out_size, void* d_ws, size_t ws_size,
                              hipStream_t stream) {
  const float* data = (const float*)d_in[0];
  const float* w1   = (const float*)d_in[1];
  const float* b1   = (const float*)d_in[2];
  const float* w2   = (const float*)d_in[3];
  const float* b2   = (const float*)d_in[4];
  const float* W    = (const float*)d_in[5];
  float* out = (float*)d_out;

  short* wstg   = (short*)d_ws;               // 10,616,832 shorts (21.2 MB)
  short* c1g    = wstg + 10616832;            // 48,234,496 shorts (96.5 MB)
  float* xcaps0 = (float*)(c1g + 48234496);   //  2,359,296 floats (9.4 MB)
  float* xcaps1 = xcaps0 + 2359296;           //  2,359,296 floats (9.4 MB)

  prep_all<<<3104, 256, 0, stream>>>(w2, (s16x8*)wstg, data, w1, b1, c1g);
  conv2_mfma<<<1024, 256, 0, stream>>>(c1g, wstg, b2, xcaps0, xcaps1);
  routing_fused<<<1280, 256, 0, stream>>>(xcaps0, xcaps1, W, out);
}